// Round 7
// baseline (688.271 us; speedup 1.0000x reference)
//
#include <hip/hip_runtime.h>

#define T_TOK 4096
#define DIN   1024
#define DOUT  1024
#define NEXP  8
#define HDIM  4096
#define RCAP  9216       // 8192 rows + 8 experts x <=127 pad (128-aligned)
#define MT128 80

typedef float f32x4 __attribute__((ext_vector_type(4)));
typedef short bf16x8 __attribute__((ext_vector_type(8)));
typedef unsigned short u16x4 __attribute__((ext_vector_type(4)));

__device__ __forceinline__ float bf2f(unsigned short u) {
    union { unsigned int i; float f; } v; v.i = ((unsigned int)u) << 16; return v.f;
}
__device__ __forceinline__ unsigned short f2bf(float f) {
    union { unsigned int i; float f; } v; v.f = f;
    unsigned int r = v.i + 0x7FFFu + ((v.i >> 16) & 1u);
    return (unsigned short)(r >> 16);
}

__global__ void init_kernel(int* cnt) {
    if (threadIdx.x < NEXP) cnt[threadIdx.x] = 0;
}

// One wave per token: fp64 gating dots, softplus, top-2, softmax, routing.
__global__ __launch_bounds__(64) void gating_kernel(
    const float* __restrict__ x, const float* __restrict__ noise,
    const float* __restrict__ gw, const float* __restrict__ gb,
    const float* __restrict__ nw, const float* __restrict__ nb,
    float* __restrict__ wout, int* __restrict__ cnt,
    int* __restrict__ tok_e, int* __restrict__ tok_slot, float* __restrict__ tok_p)
{
    int t = blockIdx.x;
    int lane = threadIdx.x;
    const float* xr = x + (size_t)t * DIN;
    double ag[NEXP], an[NEXP];
#pragma unroll
    for (int e = 0; e < NEXP; ++e) { ag[e] = 0.0; an[e] = 0.0; }
    for (int d = lane; d < DIN; d += 64) {
        double xv = (double)xr[d];
        const f32x4* g4 = (const f32x4*)(gw + (size_t)d * NEXP);
        const f32x4* n4 = (const f32x4*)(nw + (size_t)d * NEXP);
        f32x4 ga = g4[0], gbv = g4[1], na = n4[0], nbv = n4[1];
#pragma unroll
        for (int j = 0; j < 4; ++j) {
            ag[j]     += xv * (double)ga[j];
            ag[4 + j] += xv * (double)gbv[j];
            an[j]     += xv * (double)na[j];
            an[4 + j] += xv * (double)nbv[j];
        }
    }
#pragma unroll
    for (int e = 0; e < NEXP; ++e) {
        double g = ag[e], n = an[e];
#pragma unroll
        for (int m = 32; m > 0; m >>= 1) { g += __shfl_xor(g, m); n += __shfl_xor(n, m); }
        ag[e] = g; an[e] = n;
    }
    double lg[NEXP];
#pragma unroll
    for (int e = 0; e < NEXP; ++e) {
        double z = an[e] + (double)nb[e];
        double sp = fmax(z, 0.0) + log1p(exp(-fabs(z)));
        lg[e] = ag[e] + (double)gb[e] + (double)noise[(size_t)t * NEXP + e] * sp;
    }
    int i0 = 0; double v0 = lg[0];
#pragma unroll
    for (int e = 1; e < NEXP; ++e) if (lg[e] > v0) { v0 = lg[e]; i0 = e; }
    int i1 = -1; double v1 = -1.0e300;
#pragma unroll
    for (int e = 0; e < NEXP; ++e) if (e != i0 && lg[e] > v1) { v1 = lg[e]; i1 = e; }
    double d1 = exp(v1 - v0);
    float p0 = (float)(1.0 / (1.0 + d1));
    float p1 = (float)(d1 / (1.0 + d1));
    if (lane < NEXP) {
        float wv = (lane == i0) ? p0 : ((lane == i1) ? p1 : 0.0f);
        wout[(size_t)t * NEXP + lane] = wv;
    }
    if (lane == 0) {
        int s0 = atomicAdd(&cnt[i0], 1);
        int s1 = atomicAdd(&cnt[i1], 1);
        tok_e[2 * t] = i0;     tok_e[2 * t + 1] = i1;
        tok_slot[2 * t] = s0;  tok_slot[2 * t + 1] = s1;
        tok_p[2 * t] = p0;     tok_p[2 * t + 1] = p1;
    }
}

// 128-row-aligned per-expert offsets + 128-row tile map.
__global__ void prefix_kernel(const int* __restrict__ cnt, int* __restrict__ poff,
                              int* __restrict__ t2e, int* __restrict__ trow)
{
    if (threadIdx.x != 0 || blockIdx.x != 0) return;
    int base = 0, a = 0;
    for (int e = 0; e < NEXP; ++e) {
        poff[e] = base;
        int c = cnt[e];
        int nt = (c + 127) >> 7;
        for (int i = 0; i < nt; ++i) { t2e[a] = e; trow[a] = base + (i << 7); ++a; }
        base += nt << 7;
    }
    for (; a < MT128; ++a) { t2e[a] = -1; trow[a] = 0; }
}

// ---- device bodies (proven R2 structures), shared by fat kernels ----

// Transpose+convert one 64x64 tile of W [E][K][N] fp32 -> Wt [E][N][K] bf16.
// idx: e = idx>>10 (per-expert tiles == 1024 for both W1 and W2);
// rem: ky = rem>>nt_shift, nz = rem & (nt-1).
__device__ __forceinline__ void convw_body(
    const float* __restrict__ W, unsigned short* __restrict__ Wt,
    int K, int N, int nt_shift, int idx, char* smem)
{
    float (*tile)[65] = (float (*)[65])smem;
    int e = idx >> 10;
    int rem = idx & 1023;
    int k0 = (rem >> nt_shift) << 6;
    int n0 = (rem & ((1 << nt_shift) - 1)) << 6;
    int tid = threadIdx.x;
    const float* src = W + ((size_t)e * K + k0) * N + n0;
    int r = tid >> 4, c4 = (tid & 15) << 2;
#pragma unroll
    for (int i = 0; i < 4; ++i) {
        f32x4 v = *(const f32x4*)(src + (size_t)(r + (i << 4)) * N + c4);
        *(f32x4*)(&tile[r + (i << 4)][c4]) = v;
    }
    __syncthreads();
    unsigned short* dst = Wt + ((size_t)e * N + n0) * K + k0;
    int n = tid >> 2, kq = (tid & 3) << 4;
#pragma unroll
    for (int j = 0; j < 4; ++j) {
        int kk = kq + (j << 2);
        u16x4 o;
#pragma unroll
        for (int q = 0; q < 4; ++q) o[q] = f2bf(tile[kk + q][n]);
        *(u16x4*)(dst + (size_t)n * K + kk) = o;
    }
}

// 128x128 tile, BK=32, 4 waves, 2-barrier loop, global_load_lds staging with
// both-sides slot swizzle (0 bank conflicts, proven R2), optional split-K.
__device__ __forceinline__ void gemm_body(
    const unsigned short* __restrict__ A, int lda,
    const unsigned short* __restrict__ Bt, int ldb, int N, int KLEN,
    unsigned short* __restrict__ C0, unsigned short* __restrict__ C1,
    const float* __restrict__ bias,
    const int* __restrict__ t2e, const int* __restrict__ trow,
    int wg, int nbshift, int ksplit, int relu, char* smem)
{
    int tileid = wg >> (nbshift + ksplit);
    int low = wg & ((1 << (nbshift + ksplit)) - 1);
    int nb = low >> ksplit;
    int ks = ksplit ? (low & 1) : 0;

    int e = t2e[tileid];
    if (e < 0) return;
    int row0 = trow[tileid];
    int n0 = nb << 7;
    int koff = ks * KLEN;
    unsigned short* C = ks ? C1 : C0;

    unsigned short* As = (unsigned short*)smem;         // 128x32 bf16 = 8KB
    unsigned short* Bs = As + 4096;                     // 8KB

    int tid = threadIdx.x;
    int lane = tid & 63;
    int wv = tid >> 6;
    int wr = (wv >> 1) << 6;
    int wc = (wv & 1) << 6;

    const unsigned short* Ab = A + (size_t)row0 * lda + koff;
    const unsigned short* Bb = Bt + ((size_t)e * N + n0) * ldb + koff;

    f32x4 acc[4][4] = {};

    int srow = lane >> 2;
    int skc = (((lane & 3) ^ ((lane >> 3) & 3)) << 3);
    int hr = lane & 15;
    int kfrag = (((lane >> 4) ^ ((lane >> 1) & 3)) << 3);

    int nkt = KLEN >> 5;
    for (int kt = 0; kt < nkt; ++kt) {
        __syncthreads();
        int kb = kt << 5;
#pragma unroll
        for (int j = 0; j < 2; ++j) {
            int c = wv + (j << 2);
            int r = (c << 4) + srow;
            __builtin_amdgcn_global_load_lds(
                (const __attribute__((address_space(1))) void*)(Ab + (size_t)r * lda + kb + skc),
                (__attribute__((address_space(3))) void*)(&As[c << 9]), 16, 0, 0);
            __builtin_amdgcn_global_load_lds(
                (const __attribute__((address_space(1))) void*)(Bb + (size_t)r * ldb + kb + skc),
                (__attribute__((address_space(3))) void*)(&Bs[c << 9]), 16, 0, 0);
        }
        __syncthreads();
        bf16x8 af[4], bfv[4];
#pragma unroll
        for (int m = 0; m < 4; ++m)
            af[m] = *(const bf16x8*)(&As[((wr + (m << 4) + hr) << 5) + kfrag]);
#pragma unroll
        for (int n = 0; n < 4; ++n)
            bfv[n] = *(const bf16x8*)(&Bs[((wc + (n << 4) + hr) << 5) + kfrag]);
#pragma unroll
        for (int m = 0; m < 4; ++m)
#pragma unroll
            for (int n = 0; n < 4; ++n)
                acc[m][n] = __builtin_amdgcn_mfma_f32_16x16x32_bf16(af[m], bfv[n], acc[m][n], 0, 0, 0);
    }

    int rq = (lane >> 4) << 2;
    int cl = lane & 15;
#pragma unroll
    for (int n = 0; n < 4; ++n) {
        int col = wc + (n << 4) + cl;
        float bv = (ks == 0) ? bias[(size_t)e * N + n0 + col] : 0.0f;
#pragma unroll
        for (int m = 0; m < 4; ++m) {
#pragma unroll
            for (int r = 0; r < 4; ++r) {
                int row = wr + (m << 4) + rq + r;
                float v = acc[m][n][r] + bv;
                if (relu) v = fmaxf(v, 0.0f);
                C[(size_t)(row0 + row) * N + n0 + col] = f2bf(v);
            }
        }
    }
}

// ---- fat kernel A: gather (even bids) || convw W1 (odd bids) ----
__global__ __launch_bounds__(256) void gather_conv1_kernel(
    const float* __restrict__ x, const int* __restrict__ tok_e,
    const int* __restrict__ tok_slot, const int* __restrict__ poff,
    unsigned short* __restrict__ Xg,
    const float* __restrict__ w1, unsigned short* __restrict__ W1t)
{
    __shared__ __align__(16) char smem[16640];
    int bid = blockIdx.x;
    if (bid & 1) {
        convw_body(w1, W1t, DIN, HDIM, 6, bid >> 1, smem);   // 8192 tiles
        return;
    }
    int b = bid >> 1;                                        // 8192 gather rows
    int t = b >> 1, k = b & 1;
    int e = tok_e[2 * t + k];
    int row = poff[e] + tok_slot[2 * t + k];
    int c = threadIdx.x << 2;
    f32x4 v = *(const f32x4*)(x + (size_t)t * DIN + c);
    u16x4 o;
#pragma unroll
    for (int j = 0; j < 4; ++j) o[j] = f2bf(v[j]);
    *(u16x4*)(Xg + (size_t)row * DIN + c) = o;
}

// ---- fat kernel B: GEMM1 (groups g%4==0, g<1280) || convw W2 (rest) ----
// Group-of-8 interleave keeps bid%8 XCD diversity; gemm wg = sub*320 + seq
// gives each XCD a contiguous tileid chunk (n-fastest within).
__global__ __launch_bounds__(256, 4) void fat1_kernel(
    const unsigned short* __restrict__ Xg, const unsigned short* __restrict__ W1t,
    unsigned short* __restrict__ H, const float* __restrict__ b1,
    const int* __restrict__ t2e, const int* __restrict__ trow,
    const float* __restrict__ w2, unsigned short* __restrict__ W2t)
{
    __shared__ __align__(16) char smem[16640];
    int bid = blockIdx.x;
    int group = bid >> 3;
    int sub = bid & 7;
    if (group < 1280 && (group & 3) == 0) {
        int gemm_idx = ((group >> 2) << 3) + sub;            // 0..2559
        int wg = ((gemm_idx & 7) * 320) + (gemm_idx >> 3);   // XCD-chunked
        gemm_body(Xg, DIN, W1t, DIN, HDIM, DIN, H, H, b1, t2e, trow,
                  wg, 5, 0, 1, smem);
    } else {
        int rank = (group < 1280) ? (group - (group >> 2) - 1) : (group - 320);
        int cidx = (rank << 3) + sub;                        // 0..8191
        convw_body(w2, W2t, HDIM, DOUT, 4, cidx, smem);
    }
}

// GEMM2: split-K=2 (proven R6 math), XCD-chunked.
__global__ __launch_bounds__(256, 4) void gemm2_kernel(
    const unsigned short* __restrict__ H, const unsigned short* __restrict__ W2t,
    unsigned short* __restrict__ Oa, unsigned short* __restrict__ Ob,
    const float* __restrict__ b2,
    const int* __restrict__ t2e, const int* __restrict__ trow)
{
    __shared__ __align__(16) char smem[16384];
    int wg = ((blockIdx.x & 7) * 160) + (blockIdx.x >> 3);   // 1280 blocks
    gemm_body(H, HDIM, W2t, HDIM, DOUT, HDIM / 2, Oa, Ob, b2, t2e, trow,
              wg, 3, 1, 0, smem);
}

// x_out[t] = p0*(Oa[r0]+Ob[r0]) + p1*(Oa[r1]+Ob[r1])
__global__ __launch_bounds__(256) void combine_kernel(
    const unsigned short* __restrict__ Oa, const unsigned short* __restrict__ Ob,
    const int* __restrict__ tok_e, const int* __restrict__ tok_slot,
    const float* __restrict__ tok_p, const int* __restrict__ poff,
    float* __restrict__ xout)
{
    int t = blockIdx.x;
    int e0 = tok_e[2 * t], e1 = tok_e[2 * t + 1];
    int r0 = poff[e0] + tok_slot[2 * t];
    int r1 = poff[e1] + tok_slot[2 * t + 1];
    float p0 = tok_p[2 * t], p1 = tok_p[2 * t + 1];
    int c = threadIdx.x << 2;
    u16x4 a0 = *(const u16x4*)(Oa + (size_t)r0 * DOUT + c);
    u16x4 a1 = *(const u16x4*)(Ob + (size_t)r0 * DOUT + c);
    u16x4 b0 = *(const u16x4*)(Oa + (size_t)r1 * DOUT + c);
    u16x4 b1 = *(const u16x4*)(Ob + (size_t)r1 * DOUT + c);
    f32x4 r;
#pragma unroll
    for (int j = 0; j < 4; ++j)
        r[j] = p0 * (bf2f(a0[j]) + bf2f(a1[j])) + p1 * (bf2f(b0[j]) + bf2f(b1[j]));
    *(f32x4*)(xout + (size_t)t * DOUT + c) = r;
}

extern "C" void kernel_launch(void* const* d_in, const int* in_sizes, int n_in,
                              void* d_out, int out_size, void* d_ws, size_t ws_size,
                              hipStream_t stream)
{
    const float* x     = (const float*)d_in[0];
    const float* noise = (const float*)d_in[1];
    const float* gw    = (const float*)d_in[2];
    const float* gb    = (const float*)d_in[3];
    const float* nw    = (const float*)d_in[4];
    const float* nb    = (const float*)d_in[5];
    const float* w1    = (const float*)d_in[6];
    const float* b1    = (const float*)d_in[7];
    const float* w2    = (const float*)d_in[8];
    const float* b2    = (const float*)d_in[9];
    float* xout = (float*)d_out;
    float* wout = xout + (size_t)T_TOK * DOUT;

    char* ws = (char*)d_ws;
    int*   cnt      = (int*)(ws + 0);
    int*   poff     = (int*)(ws + 256);
    int*   t2e      = (int*)(ws + 512);
    int*   trow     = (int*)(ws + 1024);
    int*   tok_e    = (int*)(ws + 2048);
    int*   tok_slot = (int*)(ws + 34816);
    float* tok_p    = (float*)(ws + 67584);
    size_t oXg = 104448;                                  // 256-aligned
    unsigned short* Xg  = (unsigned short*)(ws + oXg);
    size_t oH  = oXg + (size_t)RCAP * DIN * 2;            // Xg 18.9 MB
    unsigned short* H   = (unsigned short*)(ws + oH);     // H 75.5 MB
    size_t oW1 = oH + (size_t)RCAP * HDIM * 2;
    unsigned short* W1t = (unsigned short*)(ws + oW1);    // 67.1 MB
    size_t oW2 = oW1 + (size_t)NEXP * HDIM * DIN * 2;
    unsigned short* W2t = (unsigned short*)(ws + oW2);    // 67.1 MB
    // Oa/Ob alias W1t (dead after fat1/GEMM1): 2 x 18.9 MB <= 67.1 MB
    unsigned short* Oa = W1t;
    unsigned short* Ob = W1t + (size_t)RCAP * DOUT;
    // total ~228.6 MB

    init_kernel<<<1, 64, 0, stream>>>(cnt);
    gating_kernel<<<T_TOK, 64, 0, stream>>>(x, noise, gw, gb, nw, nb,
                                            wout, cnt, tok_e, tok_slot, tok_p);
    prefix_kernel<<<1, 1, 0, stream>>>(cnt, poff, t2e, trow);
    // gather || convw W1
    gather_conv1_kernel<<<16384, 256, 0, stream>>>(x, tok_e, tok_slot, poff, Xg, w1, W1t);
    // GEMM1 (H = relu(Xg @ W1 + b1)) || convw W2
    fat1_kernel<<<10752, 256, 0, stream>>>(Xg, W1t, H, b1, t2e, trow, w2, W2t);
    // GEMM2 split-K=2: Oa = H[:,:2048] @ W2[:2048] + b2 ; Ob = H[:,2048:] @ W2[2048:]
    gemm2_kernel<<<1280, 256, 0, stream>>>(H, W2t, Oa, Ob, b2, t2e, trow);
    combine_kernel<<<T_TOK, 256, 0, stream>>>(Oa, Ob, tok_e, tok_slot, tok_p, poff, xout);
}

// Round 8
// 429.668 us; speedup vs baseline: 1.6019x; 1.6019x over previous
//
#include <hip/hip_runtime.h>

#define T_TOK 4096
#define DIN   1024
#define DOUT  1024
#define NEXP  8
#define HDIM  4096
#define RCAP  9216       // 8192 rows + 8 experts x <=127 pad (128-aligned)
#define MT128 80

typedef float f32x4 __attribute__((ext_vector_type(4)));
typedef short bf16x8 __attribute__((ext_vector_type(8)));
typedef unsigned short u16x4 __attribute__((ext_vector_type(4)));

__device__ __forceinline__ float bf2f(unsigned short u) {
    union { unsigned int i; float f; } v; v.i = ((unsigned int)u) << 16; return v.f;
}
__device__ __forceinline__ unsigned short f2bf(float f) {
    union { unsigned int i; float f; } v; v.f = f;
    unsigned int r = v.i + 0x7FFFu + ((v.i >> 16) & 1u);
    return (unsigned short)(r >> 16);
}

__global__ void init_kernel(int* cnt) {
    if (threadIdx.x < NEXP) cnt[threadIdx.x] = 0;
}

// One wave per token: fp64 gating dots, softplus, top-2, softmax, routing.
__global__ __launch_bounds__(64) void gating_kernel(
    const float* __restrict__ x, const float* __restrict__ noise,
    const float* __restrict__ gw, const float* __restrict__ gb,
    const float* __restrict__ nw, const float* __restrict__ nb,
    float* __restrict__ wout, int* __restrict__ cnt,
    int* __restrict__ tok_e, int* __restrict__ tok_slot, float* __restrict__ tok_p)
{
    int t = blockIdx.x;
    int lane = threadIdx.x;
    const float* xr = x + (size_t)t * DIN;
    double ag[NEXP], an[NEXP];
#pragma unroll
    for (int e = 0; e < NEXP; ++e) { ag[e] = 0.0; an[e] = 0.0; }
    for (int d = lane; d < DIN; d += 64) {
        double xv = (double)xr[d];
        const f32x4* g4 = (const f32x4*)(gw + (size_t)d * NEXP);
        const f32x4* n4 = (const f32x4*)(nw + (size_t)d * NEXP);
        f32x4 ga = g4[0], gbv = g4[1], na = n4[0], nbv = n4[1];
#pragma unroll
        for (int j = 0; j < 4; ++j) {
            ag[j]     += xv * (double)ga[j];
            ag[4 + j] += xv * (double)gbv[j];
            an[j]     += xv * (double)na[j];
            an[4 + j] += xv * (double)nbv[j];
        }
    }
#pragma unroll
    for (int e = 0; e < NEXP; ++e) {
        double g = ag[e], n = an[e];
#pragma unroll
        for (int m = 32; m > 0; m >>= 1) { g += __shfl_xor(g, m); n += __shfl_xor(n, m); }
        ag[e] = g; an[e] = n;
    }
    double lg[NEXP];
#pragma unroll
    for (int e = 0; e < NEXP; ++e) {
        double z = an[e] + (double)nb[e];
        double sp = fmax(z, 0.0) + log1p(exp(-fabs(z)));
        lg[e] = ag[e] + (double)gb[e] + (double)noise[(size_t)t * NEXP + e] * sp;
    }
    int i0 = 0; double v0 = lg[0];
#pragma unroll
    for (int e = 1; e < NEXP; ++e) if (lg[e] > v0) { v0 = lg[e]; i0 = e; }
    int i1 = -1; double v1 = -1.0e300;
#pragma unroll
    for (int e = 0; e < NEXP; ++e) if (e != i0 && lg[e] > v1) { v1 = lg[e]; i1 = e; }
    double d1 = exp(v1 - v0);
    float p0 = (float)(1.0 / (1.0 + d1));
    float p1 = (float)(d1 / (1.0 + d1));
    if (lane < NEXP) {
        float wv = (lane == i0) ? p0 : ((lane == i1) ? p1 : 0.0f);
        wout[(size_t)t * NEXP + lane] = wv;
    }
    if (lane == 0) {
        int s0 = atomicAdd(&cnt[i0], 1);
        int s1 = atomicAdd(&cnt[i1], 1);
        tok_e[2 * t] = i0;     tok_e[2 * t + 1] = i1;
        tok_slot[2 * t] = s0;  tok_slot[2 * t + 1] = s1;
        tok_p[2 * t] = p0;     tok_p[2 * t + 1] = p1;
    }
}

// 128-row-aligned per-expert offsets + 128-row tile map.
__global__ void prefix_kernel(const int* __restrict__ cnt, int* __restrict__ poff,
                              int* __restrict__ t2e, int* __restrict__ trow)
{
    if (threadIdx.x != 0 || blockIdx.x != 0) return;
    int base = 0, a = 0;
    for (int e = 0; e < NEXP; ++e) {
        poff[e] = base;
        int c = cnt[e];
        int nt = (c + 127) >> 7;
        for (int i = 0; i < nt; ++i) { t2e[a] = e; trow[a] = base + (i << 7); ++a; }
        base += nt << 7;
    }
    for (; a < MT128; ++a) { t2e[a] = -1; trow[a] = 0; }
}

// Copy token row t (fp32) to its expert slot as bf16.
__global__ __launch_bounds__(256) void gather_kernel(
    const float* __restrict__ x, const int* __restrict__ tok_e,
    const int* __restrict__ tok_slot, const int* __restrict__ poff,
    unsigned short* __restrict__ Xg)
{
    int b = blockIdx.x;
    int t = b >> 1, k = b & 1;
    int e = tok_e[2 * t + k];
    int row = poff[e] + tok_slot[2 * t + k];
    int c = threadIdx.x << 2;
    f32x4 v = *(const f32x4*)(x + (size_t)t * DIN + c);
    u16x4 o;
#pragma unroll
    for (int j = 0; j < 4; ++j) o[j] = f2bf(v[j]);
    *(u16x4*)(Xg + (size_t)row * DIN + c) = o;
}

// Transpose+convert: W [E][K][N] fp32 -> Wt [E][N][K] bf16 (64x64 LDS tiles).
__global__ __launch_bounds__(256) void convw_kernel(
    const float* __restrict__ W, unsigned short* __restrict__ Wt, int K, int N)
{
    __shared__ float tile[64][65];
    int e = blockIdx.x;
    int k0 = blockIdx.y << 6;
    int n0 = blockIdx.z << 6;
    int tid = threadIdx.x;
    const float* src = W + ((size_t)e * K + k0) * N + n0;
    int r = tid >> 4, c4 = (tid & 15) << 2;
#pragma unroll
    for (int i = 0; i < 4; ++i) {
        f32x4 v = *(const f32x4*)(src + (size_t)(r + (i << 4)) * N + c4);
        *(f32x4*)(&tile[r + (i << 4)][c4]) = v;
    }
    __syncthreads();
    unsigned short* dst = Wt + ((size_t)e * N + n0) * K + k0;
    int n = tid >> 2, kq = (tid & 3) << 4;
#pragma unroll
    for (int j = 0; j < 4; ++j) {
        int kk = kq + (j << 2);
        u16x4 o;
#pragma unroll
        for (int q = 0; q < 4; ++q) o[q] = f2bf(tile[kk + q][n]);
        *(u16x4*)(dst + (size_t)n * K + kk) = o;
    }
}

// 128x128 tile, BK=64, 4 waves, 2-barrier loop (R2 structure, half the
// latency exposures), both-sides slot swizzle for 64-elem rows:
//   LDS[r*64 + ((k>>3 ^ (r&7))<<3) + (k&7)] = X[r][k]
// Staged linear-dest (u = i*256+tid, r=u>>3, slot=tid&7, source pre-swizzled);
// read with same involution; 16 lanes/frag spread over all 8 slots (2-way, free).
__global__ __launch_bounds__(256, 2) void gemm64_kernel(
    const unsigned short* __restrict__ A, int lda,
    const unsigned short* __restrict__ Bt, int ldb, int N, int KLEN,
    unsigned short* __restrict__ C,
    const float* __restrict__ bias,
    const int* __restrict__ t2e, const int* __restrict__ trow,
    int nbshift, int relu)
{
    int nwg = gridDim.x;
    int cpx = nwg >> 3;
    int wg = ((blockIdx.x & 7) * cpx) + (blockIdx.x >> 3);
    int tileid = wg >> nbshift;
    int nb = wg & ((1 << nbshift) - 1);

    int e = t2e[tileid];
    if (e < 0) return;
    int row0 = trow[tileid];
    int n0 = nb << 7;

    __shared__ __align__(16) unsigned short As[128 * 64];   // 16KB
    __shared__ __align__(16) unsigned short Bs[128 * 64];   // 16KB

    int tid = threadIdx.x;
    int lane = tid & 63;
    int wv = tid >> 6;
    int wr = (wv >> 1) << 6;
    int wc = (wv & 1) << 6;

    const unsigned short* Ab = A + (size_t)row0 * lda;
    const unsigned short* Bb = Bt + ((size_t)e * N + n0) * ldb;

    f32x4 acc[4][4] = {};

    // staging: unit u = i*256+tid -> r = u>>3 (= i*32 + (tid>>3)), phys slot = tid&7
    int sr_lo = tid >> 3;                 // row within 32-row group
    int sp = tid & 7;                     // physical 16B slot
    // read-side: lane hr = lane&15, k-slot s_log = kq*4 + (lane>>4)
    int hr = lane & 15;
    int q4 = lane >> 4;

    int nkt = KLEN >> 6;
    for (int kt = 0; kt < nkt; ++kt) {
        __syncthreads();
        int kb = kt << 6;
#pragma unroll
        for (int i = 0; i < 4; ++i) {
            int r = (i << 5) + sr_lo;
            int col = ((sp ^ (r & 7)) << 3);
            int u = (i << 8) + tid;
            __builtin_amdgcn_global_load_lds(
                (const __attribute__((address_space(1))) void*)(Ab + (size_t)r * lda + kb + col),
                (__attribute__((address_space(3))) void*)(&As[u << 3]), 16, 0, 0);
            __builtin_amdgcn_global_load_lds(
                (const __attribute__((address_space(1))) void*)(Bb + (size_t)r * ldb + kb + col),
                (__attribute__((address_space(3))) void*)(&Bs[u << 3]), 16, 0, 0);
        }
        __syncthreads();
#pragma unroll
        for (int kq = 0; kq < 2; ++kq) {
            int slog = (kq << 2) | q4;
            bf16x8 af[4], bfv[4];
#pragma unroll
            for (int m = 0; m < 4; ++m) {
                int r = wr + (m << 4) + hr;
                af[m] = *(const bf16x8*)(&As[(r << 6) + ((slog ^ (r & 7)) << 3)]);
            }
#pragma unroll
            for (int n = 0; n < 4; ++n) {
                int r = wc + (n << 4) + hr;
                bfv[n] = *(const bf16x8*)(&Bs[(r << 6) + ((slog ^ (r & 7)) << 3)]);
            }
#pragma unroll
            for (int m = 0; m < 4; ++m)
#pragma unroll
                for (int n = 0; n < 4; ++n)
                    acc[m][n] = __builtin_amdgcn_mfma_f32_16x16x32_bf16(af[m], bfv[n], acc[m][n], 0, 0, 0);
        }
    }

    int rq = q4 << 2;
    int cl = hr;
#pragma unroll
    for (int n = 0; n < 4; ++n) {
        int col = wc + (n << 4) + cl;
        float bv = bias[(size_t)e * N + n0 + col];
#pragma unroll
        for (int m = 0; m < 4; ++m) {
#pragma unroll
            for (int r = 0; r < 4; ++r) {
                int row = wr + (m << 4) + rq + r;
                float v = acc[m][n][r] + bv;
                if (relu) v = fmaxf(v, 0.0f);
                C[(size_t)(row0 + row) * N + n0 + col] = f2bf(v);
            }
        }
    }
}

// x_out[t] = p0*O[row0] + p1*O[row1]
__global__ __launch_bounds__(256) void combine_kernel(
    const unsigned short* __restrict__ O, const int* __restrict__ tok_e,
    const int* __restrict__ tok_slot, const float* __restrict__ tok_p,
    const int* __restrict__ poff, float* __restrict__ xout)
{
    int t = blockIdx.x;
    int e0 = tok_e[2 * t], e1 = tok_e[2 * t + 1];
    int r0 = poff[e0] + tok_slot[2 * t];
    int r1 = poff[e1] + tok_slot[2 * t + 1];
    float p0 = tok_p[2 * t], p1 = tok_p[2 * t + 1];
    int c = threadIdx.x << 2;
    u16x4 a = *(const u16x4*)(O + (size_t)r0 * DOUT + c);
    u16x4 b = *(const u16x4*)(O + (size_t)r1 * DOUT + c);
    f32x4 r;
#pragma unroll
    for (int j = 0; j < 4; ++j) r[j] = p0 * bf2f(a[j]) + p1 * bf2f(b[j]);
    *(f32x4*)(xout + (size_t)t * DOUT + c) = r;
}

extern "C" void kernel_launch(void* const* d_in, const int* in_sizes, int n_in,
                              void* d_out, int out_size, void* d_ws, size_t ws_size,
                              hipStream_t stream)
{
    const float* x     = (const float*)d_in[0];
    const float* noise = (const float*)d_in[1];
    const float* gw    = (const float*)d_in[2];
    const float* gb    = (const float*)d_in[3];
    const float* nw    = (const float*)d_in[4];
    const float* nb    = (const float*)d_in[5];
    const float* w1    = (const float*)d_in[6];
    const float* b1    = (const float*)d_in[7];
    const float* w2    = (const float*)d_in[8];
    const float* b2    = (const float*)d_in[9];
    float* xout = (float*)d_out;
    float* wout = xout + (size_t)T_TOK * DOUT;

    char* ws = (char*)d_ws;
    int*   cnt      = (int*)(ws + 0);
    int*   poff     = (int*)(ws + 256);
    int*   t2e      = (int*)(ws + 512);
    int*   trow     = (int*)(ws + 1024);
    int*   tok_e    = (int*)(ws + 2048);
    int*   tok_slot = (int*)(ws + 34816);
    float* tok_p    = (float*)(ws + 67584);
    size_t oXg = 104448;                                  // 256-aligned
    unsigned short* Xg  = (unsigned short*)(ws + oXg);
    unsigned short* O   = Xg;                             // O aliases Xg (dead after GEMM1)
    size_t oH  = oXg + (size_t)RCAP * DIN * 2;            // Xg 18.9 MB
    unsigned short* H   = (unsigned short*)(ws + oH);     // H 75.5 MB
    size_t oW1 = oH + (size_t)RCAP * HDIM * 2;
    unsigned short* W1t = (unsigned short*)(ws + oW1);    // 67.1 MB
    size_t oW2 = oW1 + (size_t)NEXP * HDIM * DIN * 2;
    unsigned short* W2t = (unsigned short*)(ws + oW2);    // 67.1 MB
    // total ~228.6 MB

    init_kernel<<<1, 64, 0, stream>>>(cnt);
    gating_kernel<<<T_TOK, 64, 0, stream>>>(x, noise, gw, gb, nw, nb,
                                            wout, cnt, tok_e, tok_slot, tok_p);
    prefix_kernel<<<1, 1, 0, stream>>>(cnt, poff, t2e, trow);
    gather_kernel<<<2 * T_TOK, 256, 0, stream>>>(x, tok_e, tok_slot, poff, Xg);
    convw_kernel<<<dim3(NEXP, DIN / 64, HDIM / 64), 256, 0, stream>>>(w1, W1t, DIN, HDIM);
    convw_kernel<<<dim3(NEXP, HDIM / 64, DOUT / 64), 256, 0, stream>>>(w2, W2t, HDIM, DOUT);
    // GEMM1: H = relu(Xg @ W1[e] + b1)
    gemm64_kernel<<<MT128 * 32, 256, 0, stream>>>(
        Xg, DIN, W1t, DIN, HDIM, DIN, H, b1, t2e, trow, 5, 1);
    // GEMM2: O = H @ W2[e] + b2
    gemm64_kernel<<<MT128 * 8, 256, 0, stream>>>(
        H, HDIM, W2t, HDIM, DOUT, HDIM, O, b2, t2e, trow, 3, 0);
    combine_kernel<<<T_TOK, 256, 0, stream>>>(O, tok_e, tok_slot, tok_p, poff, xout);
}